// Round 10
// baseline (522.280 us; speedup 1.0000x reference)
//
#include <hip/hip_runtime.h>
#include <cstdint>
#include <cstddef>

#define B_  2
#define H_  8
#define C_  2048
#define HW_ 64
#define HD_ 512   // H_*HW_

typedef __attribute__((ext_vector_type(8))) short short8;
typedef __attribute__((ext_vector_type(4))) short short4v;
typedef __attribute__((ext_vector_type(4))) float f32x4;
typedef __attribute__((ext_vector_type(4))) int   int4v;
typedef unsigned short us;

static __device__ inline us f2bf(float f) {           // RNE
    unsigned u = __builtin_bit_cast(unsigned, f);
    u = u + 0x7FFFu + ((u >> 16) & 1u);
    return (us)(u >> 16);
}
static __device__ inline us f2bf_t(float f) {         // truncate (hot path)
    return (us)(__builtin_bit_cast(unsigned, f) >> 16);
}
static __device__ inline float bf2f(us s) {
    unsigned u = ((unsigned)s) << 16;
    return __builtin_bit_cast(float, u);
}
static __device__ inline f32x4 mfma16(short8 a, short8 b, f32x4 c) {
    return __builtin_amdgcn_mfma_f32_16x16x32_bf16(a, b, c, 0, 0, 0);
}
static __device__ inline short8 negbf(short8 v) {
    int4v u = __builtin_bit_cast(int4v, v);
    u ^= (int)0x80008000;
    return __builtin_bit_cast(short8, u);
}
// b64-pair LDS fragment load (rows padded to 68 shorts -> only 8B-aligned)
static __device__ inline short8 lds_frag(const us* p) {
    short4v a = *(const short4v*)p;
    short4v b = *(const short4v*)(p + 4);
    return __builtin_shufflevector(a, b, 0, 1, 2, 3, 4, 5, 6, 7);
}

// ---------------- Projection + rotary phase ----------------
// W staged TRANSPOSED [j][i] (stride 68, 16B-aligned rows) -> float4 inner
// loop: 176 LDS inst/thread vs 704 scalar (R7). sx reads are wave-uniform.
__global__ __launch_bounds__(256) void proj_kernel(
    const float* __restrict__ x, const float* __restrict__ WQ,
    const float* __restrict__ WK, const float* __restrict__ WV,
    const float* __restrict__ theta,
    us* __restrict__ Qch, us* __restrict__ Qcl,
    us* __restrict__ K1h, us* __restrict__ K1l,
    us* __restrict__ VTh, us* __restrict__ VTl)
{
    __shared__ float smem[3 * 64 * 68 + 32 * 68];   // 60,928 B
    float* sWT = smem;               // [3][64 j][68 i]
    float* sx  = smem + 3 * 64 * 68; // [32 c][68 i]
    int tid = threadIdx.x;
    int bh = blockIdx.y; int h = bh & 7;
    int c0 = blockIdx.x * 32;
    #pragma unroll
    for (int t = tid; t < 1024; t += 256) {
        int j4 = (t & 15) * 4, i = t >> 4;
        float4 wq = *(const float4*)&WQ[(h * 64 + i) * 64 + j4];
        float4 wk = *(const float4*)&WK[(h * 64 + i) * 64 + j4];
        float4 wv = *(const float4*)&WV[(h * 64 + i) * 64 + j4];
        sWT[(j4 + 0) * 68 + i] = wq.x; sWT[(j4 + 1) * 68 + i] = wq.y;
        sWT[(j4 + 2) * 68 + i] = wq.z; sWT[(j4 + 3) * 68 + i] = wq.w;
        sWT[64 * 68 + (j4 + 0) * 68 + i] = wk.x; sWT[64 * 68 + (j4 + 1) * 68 + i] = wk.y;
        sWT[64 * 68 + (j4 + 2) * 68 + i] = wk.z; sWT[64 * 68 + (j4 + 3) * 68 + i] = wk.w;
        sWT[2 * 64 * 68 + (j4 + 0) * 68 + i] = wv.x; sWT[2 * 64 * 68 + (j4 + 1) * 68 + i] = wv.y;
        sWT[2 * 64 * 68 + (j4 + 2) * 68 + i] = wv.z; sWT[2 * 64 * 68 + (j4 + 3) * 68 + i] = wv.w;
    }
    #pragma unroll
    for (int t = tid; t < 512; t += 256) {
        int i4 = (t & 15) * 4, c = t >> 4;
        *(float4*)&sx[c * 68 + i4] =
            *(const float4*)&x[((size_t)((bh >> 3) * C_ + c0 + c)) * HD_ + h * 64 + i4];
    }
    __syncthreads();
    int j = tid & 63, cg = tid >> 6;     // cg uniform per wave
    float aq[8] = {}, ak[8] = {}, av[8] = {};
    const float* pw0 = &sWT[j * 68];
    const float* pw1 = &sWT[64 * 68 + j * 68];
    const float* pw2 = &sWT[2 * 64 * 68 + j * 68];
    const float* px  = &sx[cg * 8 * 68];
    #pragma unroll
    for (int i0 = 0; i0 < 64; i0 += 4) {
        float4 w0 = *(const float4*)(pw0 + i0);
        float4 w1 = *(const float4*)(pw1 + i0);
        float4 w2 = *(const float4*)(pw2 + i0);
        #pragma unroll
        for (int cc = 0; cc < 8; ++cc) {
            float4 xv = *(const float4*)(px + cc * 68 + i0);
            aq[cc] += xv.x * w0.x + xv.y * w0.y + xv.z * w0.z + xv.w * w0.w;
            ak[cc] += xv.x * w1.x + xv.y * w1.y + xv.z * w1.z + xv.w * w1.w;
            av[cc] += xv.x * w2.x + xv.y * w2.y + xv.z * w2.z + xv.w * w2.w;
        }
    }
    float th = theta[h * 64 + j];
    #pragma unroll
    for (int cc = 0; cc < 8; ++cc) {
        int c = c0 + cg * 8 + cc;
        float sn, cs;
        sincosf((float)c * th, &sn, &cs);
        float qr = aq[cc] * cs, qi = aq[cc] * sn;
        float kr = ak[cc] * cs, nki = ak[cc] * sn;   // nki = -Ki
        size_t rq = ((size_t)bh * C_ + c) * 128;
        us h0;
        h0 = f2bf(qr);  Qch[rq + j]      = h0; Qcl[rq + j]      = f2bf(qr  - bf2f(h0));
        h0 = f2bf(qi);  Qch[rq + 64 + j] = h0; Qcl[rq + 64 + j] = f2bf(qi  - bf2f(h0));
        h0 = f2bf(kr);  K1h[rq + j]      = h0; K1l[rq + j]      = f2bf(kr  - bf2f(h0));
        h0 = f2bf(nki); K1h[rq + 64 + j] = h0; K1l[rq + 64 + j] = f2bf(nki - bf2f(h0));
    }
    __syncthreads();
    float* T0 = smem;                   // [64][33]
    #pragma unroll
    for (int cc = 0; cc < 8; ++cc)
        T0[j * 33 + cg * 8 + cc] = av[cc];
    __syncthreads();
    int cc2 = tid & 31, jg = tid >> 5;
    #pragma unroll
    for (int jj = 0; jj < 8; ++jj) {
        int jr = jg * 8 + jj;
        float v = T0[jr * 33 + cc2];
        us hh = f2bf(v);
        size_t o = ((size_t)bh * 64 + jr) * C_ + c0 + cc2;
        VTh[o] = hh;
        VTl[o] = f2bf(v - bf2f(hh));
    }
}

// ---------------- MFMA Retention (split-K partials) ----------------
// Exact R7 structure (161 us measured: V staged in LDS, K from global, S
// round-trip through LDS, 52,224 B -> 3 blocks/CU) with a BALANCED schedule:
// CU c hosts blocks {c, c+256, c+512} = parts {t, 16+t, 32+t}; part sizes
// chosen so every triple sums to exactly 33 kt-units (R7 spread was 26..40).
__global__ __launch_bounds__(256) void retention_kernel(
    const us* __restrict__ Qch, const us* __restrict__ Qcl,
    const us* __restrict__ K1h, const us* __restrict__ K1l,
    const us* __restrict__ VTh, const us* __restrict__ VTl,
    float* __restrict__ Pbuf,
    const float* __restrict__ gamma, const float* __restrict__ qk_scale)
{
    constexpr int SP = 68;
    constexpr int PL = 64 * SP;
    __shared__ us smem[6 * PL];        // 52,224 B -> 3 blocks/CU
    us* sSrh = smem;
    us* sSrl = smem + PL;
    us* sSih = smem + 2 * PL;
    us* sSil = smem + 3 * PL;
    us* sVh  = smem + 4 * PL;
    us* sVl  = smem + 5 * PL;

    const int tid = threadIdx.x;
    const int w = tid >> 6, lane = tid & 63;
    const int ln = lane & 15, quad = lane >> 4;
    const int r = (int)blockIdx.x >> 4, bh = (int)blockIdx.x & 15;
    const int h = bh & 7;
    // balanced decode: pos = r>>4, t = r&15; triple sums = 33 units
    const int pos = r >> 4, t = r & 15;
    int qt, klo, khi, slot;
    if (pos == 0)      { qt = 16 + t; klo = 0; khi = 15; slot = 16 + 2 * t; }
    else if (pos == 1) {
        if (t <= 13)      { qt = 14 - t; klo = 0;  khi = qt; slot = qt; }
        else if (t == 14) { qt = 15;     klo = 0;  khi = 15; slot = 15; }
        else              { qt = 31;     klo = 16; khi = 31; slot = 47; }
    } else {
        if (t <= 13)      { qt = 17 + t; klo = 16; khi = qt; slot = 19 + 2 * t; }
        else if (t == 14) { qt = 0;      klo = 0;  khi = 0;  slot = 0; }
        else              { qt = 16;     klo = 16; khi = 16; slot = 17; }
    }
    const int qc0 = qt * 64;
    const float lg = log2f(gamma[h]);
    const float inv_scale = 1.0f / qk_scale[0];
    float rowf[4], colf[4];
    #pragma unroll
    for (int rr2 = 0; rr2 < 4; ++rr2)
        rowf[rr2] = exp2f(lg * (float)(w * 16 + quad * 4 + rr2));
    #pragma unroll
    for (int nt = 0; nt < 4; ++nt)
        colf[nt] = exp2f(-lg * (float)(nt * 16 + ln));

    short8 Qh[4], Ql[4];
    {
        size_t qrow = ((size_t)bh * C_ + qc0 + w * 16 + ln) * 128;
        #pragma unroll
        for (int ck = 0; ck < 4; ++ck) {
            size_t off = qrow + ck * 32 + quad * 8;
            Qh[ck] = *(const short8*)(Qch + off);
            Ql[ck] = *(const short8*)(Qcl + off);
        }
    }
    f32x4 zz = {0.0f, 0.0f, 0.0f, 0.0f};
    f32x4 Or[4], Oi[4];
    #pragma unroll
    for (int it = 0; it < 4; ++it) { Or[it] = zz; Oi[it] = zz; }

    const size_t vtb = (size_t)bh * 64 * C_;
    for (int kt = klo; kt <= khi; ++kt) {
        const int kc0 = kt * 64;
        __syncthreads();
        {
            int i = tid >> 2, seg = (tid & 3) * 16;
            size_t g = vtb + (size_t)i * C_ + kc0 + seg;
            short8 a = *(const short8*)(VTh + g);
            short8 bq = *(const short8*)(VTh + g + 8);
            *(short4v*)&sVh[i * SP + seg]      = __builtin_shufflevector(a, a, 0, 1, 2, 3);
            *(short4v*)&sVh[i * SP + seg + 4]  = __builtin_shufflevector(a, a, 4, 5, 6, 7);
            *(short4v*)&sVh[i * SP + seg + 8]  = __builtin_shufflevector(bq, bq, 0, 1, 2, 3);
            *(short4v*)&sVh[i * SP + seg + 12] = __builtin_shufflevector(bq, bq, 4, 5, 6, 7);
            a  = *(const short8*)(VTl + g);
            bq = *(const short8*)(VTl + g + 8);
            *(short4v*)&sVl[i * SP + seg]      = __builtin_shufflevector(a, a, 0, 1, 2, 3);
            *(short4v*)&sVl[i * SP + seg + 4]  = __builtin_shufflevector(a, a, 4, 5, 6, 7);
            *(short4v*)&sVl[i * SP + seg + 8]  = __builtin_shufflevector(bq, bq, 0, 1, 2, 3);
            *(short4v*)&sVl[i * SP + seg + 12] = __builtin_shufflevector(bq, bq, 4, 5, 6, 7);
        }
        const float tf = exp2f(lg * (float)(qc0 - kc0)) * inv_scale;
        float tr[4];
        #pragma unroll
        for (int rr2 = 0; rr2 < 4; ++rr2) tr[rr2] = tf * rowf[rr2];
        const bool diag = (kt == qt);
        #pragma unroll
        for (int nt = 0; nt < 4; ++nt) {
            short8 Kh[4], Kl[4];
            size_t krow = ((size_t)bh * C_ + kc0 + nt * 16 + ln) * 128;
            #pragma unroll
            for (int ck = 0; ck < 4; ++ck) {
                size_t off = krow + ck * 32 + quad * 8;
                Kh[ck] = *(const short8*)(K1h + off);
                Kl[ck] = *(const short8*)(K1l + off);
            }
            f32x4 sr = zz, si = zz;
            #pragma unroll
            for (int ck = 0; ck < 4; ++ck) {
                sr = mfma16(Qh[ck], Kh[ck], sr);
                sr = mfma16(Qh[ck], Kl[ck], sr);
                sr = mfma16(Ql[ck], Kh[ck], sr);
            }
            short8 nKh2 = negbf(Kh[2]), nKh3 = negbf(Kh[3]);
            short8 nKl2 = negbf(Kl[2]), nKl3 = negbf(Kl[3]);
            si = mfma16(Qh[0], nKh2, si); si = mfma16(Qh[0], nKl2, si); si = mfma16(Ql[0], nKh2, si);
            si = mfma16(Qh[1], nKh3, si); si = mfma16(Qh[1], nKl3, si); si = mfma16(Ql[1], nKh3, si);
            si = mfma16(Qh[2], Kh[0], si); si = mfma16(Qh[2], Kl[0], si); si = mfma16(Ql[2], Kh[0], si);
            si = mfma16(Qh[3], Kh[1], si); si = mfma16(Qh[3], Kl[1], si); si = mfma16(Ql[3], Kh[1], si);
            const int kL = nt * 16 + ln;
            #pragma unroll
            for (int rr2 = 0; rr2 < 4; ++rr2) {
                float wv = tr[rr2] * colf[nt];
                if (diag && (w * 16 + quad * 4 + rr2 < kL)) wv = 0.0f;
                float a = sr[rr2] * wv, c = si[rr2] * wv;
                int ad = (w * 16 + quad * 4 + rr2) * SP + nt * 16 + ln;
                us h0 = f2bf_t(a); sSrh[ad] = h0; sSrl[ad] = f2bf_t(a - bf2f(h0));
                us h1 = f2bf_t(c); sSih[ad] = h1; sSil[ad] = f2bf_t(c - bf2f(h1));
            }
        }
        __syncthreads();
        short8 SrH[2], SrL[2], SiH[2], SiL[2];
        int sb = (w * 16 + ln) * SP;
        #pragma unroll
        for (int ck2 = 0; ck2 < 2; ++ck2) {
            int off = sb + ck2 * 32 + quad * 8;
            SrH[ck2] = lds_frag(&sSrh[off]);
            SrL[ck2] = lds_frag(&sSrl[off]);
            SiH[ck2] = lds_frag(&sSih[off]);
            SiL[ck2] = lds_frag(&sSil[off]);
        }
        #pragma unroll
        for (int it = 0; it < 4; ++it) {
            int vb = (it * 16 + ln) * SP;
            #pragma unroll
            for (int ck2 = 0; ck2 < 2; ++ck2) {
                short8 Vh = lds_frag(&sVh[vb + ck2 * 32 + quad * 8]);
                short8 Vl = lds_frag(&sVl[vb + ck2 * 32 + quad * 8]);
                Or[it] = mfma16(SrH[ck2], Vh, Or[it]);
                Or[it] = mfma16(SrH[ck2], Vl, Or[it]);
                Or[it] = mfma16(SrL[ck2], Vh, Or[it]);
                Oi[it] = mfma16(SiH[ck2], Vh, Oi[it]);
                Oi[it] = mfma16(SiH[ck2], Vl, Oi[it]);
                Oi[it] = mfma16(SiL[ck2], Vh, Oi[it]);
            }
        }
    }
    float* Pr = Pbuf + ((size_t)(bh * 48 + slot)) * 8192;
    float* Pi = Pr + 4096;
    #pragma unroll
    for (int it = 0; it < 4; ++it) {
        #pragma unroll
        for (int rr2 = 0; rr2 < 4; ++rr2) {
            int qL = w * 16 + quad * 4 + rr2, iX = it * 16 + ln;
            Pr[qL * 64 + iX] = Or[it][rr2];
            Pi[qL * 64 + iX] = Oi[it][rr2];
        }
    }
}

// -------- Merged: partial reduce + L2 norm -> A1   AND   weight cvt --------
// grid (64, 16): bx<32 -> reduce (qt=bx, bh=by); bx>=32 -> wcvt tile.
__global__ __launch_bounds__(256) void reduce_wcvt_kernel(
    const float* __restrict__ Pbuf,
    us* __restrict__ A1h, us* __restrict__ A1l,
    const float* __restrict__ WG, const float* __restrict__ WO,
    us* __restrict__ Gh, us* __restrict__ Gl,
    us* __restrict__ Oh, us* __restrict__ Ol)
{
    __shared__ float T[32 * 33];
    if ((int)blockIdx.x < 32) {
        const int qt = blockIdx.x, bh = blockIdx.y;
        const int h = bh & 7, b = bh >> 3;
        const int t = threadIdx.x;
        const int q = t >> 2, i0 = (t & 3) * 16;
        const int slot0 = (qt < 16) ? qt : 16 + 2 * (qt - 16);
        const int nparts = (qt < 16) ? 1 : 2;
        const float* P0 = Pbuf + ((size_t)(bh * 48 + slot0)) * 8192 + q * 64 + i0;
        float orv[16], oiv[16];
        #pragma unroll
        for (int s4 = 0; s4 < 4; ++s4) {
            *(float4*)&orv[s4 * 4] = *(const float4*)(P0 + s4 * 4);
            *(float4*)&oiv[s4 * 4] = *(const float4*)(P0 + 4096 + s4 * 4);
        }
        if (nparts == 2) {
            const float* P1 = P0 + 8192;
            #pragma unroll
            for (int s4 = 0; s4 < 4; ++s4) {
                float4 a = *(const float4*)(P1 + s4 * 4);
                float4 c = *(const float4*)(P1 + 4096 + s4 * 4);
                orv[s4 * 4]     += a.x; orv[s4 * 4 + 1] += a.y;
                orv[s4 * 4 + 2] += a.z; orv[s4 * 4 + 3] += a.w;
                oiv[s4 * 4]     += c.x; oiv[s4 * 4 + 1] += c.y;
                oiv[s4 * 4 + 2] += c.z; oiv[s4 * 4 + 3] += c.w;
            }
        }
        float ss = 0.0f;
        #pragma unroll
        for (int k = 0; k < 16; ++k) ss += orv[k] * orv[k] + oiv[k] * oiv[k];
        ss += __shfl_xor(ss, 1);
        ss += __shfl_xor(ss, 2);
        float rn = rsqrtf(ss);
        const size_t N1 = (size_t)B_ * H_ * C_ * HW_;
        size_t o = (((size_t)(b * C_ + qt * 64 + q)) * H_ + h) * HW_ + i0;
        us th[16], tl[16];
        #pragma unroll
        for (int k = 0; k < 16; ++k) {
            float v = orv[k] * rn;
            us hh = f2bf(v); th[k] = hh; tl[k] = f2bf(v - bf2f(hh));
        }
        *(short8*)&A1h[o] = *(short8*)&th[0]; *(short8*)&A1h[o + 8] = *(short8*)&th[8];
        *(short8*)&A1l[o] = *(short8*)&tl[0]; *(short8*)&A1l[o + 8] = *(short8*)&tl[8];
        #pragma unroll
        for (int k = 0; k < 16; ++k) {
            float v = oiv[k] * rn;
            us hh = f2bf(v); th[k] = hh; tl[k] = f2bf(v - bf2f(hh));
        }
        *(short8*)&A1h[N1 + o] = *(short8*)&th[0]; *(short8*)&A1h[N1 + o + 8] = *(short8*)&th[8];
        *(short8*)&A1l[N1 + o] = *(short8*)&tl[0]; *(short8*)&A1l[N1 + o + 8] = *(short8*)&tl[8];
    } else {
        int widx = ((int)blockIdx.x - 32) * 16 + (int)blockIdx.y;  // 0..511
        int z = widx >> 8, w2 = widx & 255;
        const float* src = z ? WO : WG;
        us* dh = z ? Oh : Gh;
        us* dl = z ? Ol : Gl;
        int k0 = (w2 >> 4) * 32, n0 = (w2 & 15) * 32;
        int c = threadIdx.x & 31, r8 = threadIdx.x >> 5;
        #pragma unroll
        for (int rr = 0; rr < 4; ++rr) {
            int rw = r8 * 4 + rr;
            T[rw * 33 + c] = src[(size_t)(k0 + rw) * 512 + n0 + c];
        }
        __syncthreads();
        #pragma unroll
        for (int rr = 0; rr < 4; ++rr) {
            int rw = r8 * 4 + rr;           // n-local
            float v = T[c * 33 + rw];       // [k-local=c][n-local=rw]
            us hh = f2bf(v);
            size_t o = (size_t)(n0 + rw) * 512 + k0 + c;
            dh[o] = hh; dl[o] = f2bf(v - bf2f(hh));
        }
    }
}

// ---------------- split-bf16 MFMA GEMM: C[8192,512] = A * W (WT given) -----
__global__ __launch_bounds__(256) void gemm_mfma_kernel(
    const us* __restrict__ Ah, const us* __restrict__ Al,
    const us* __restrict__ BTh, const us* __restrict__ BTl,
    float* __restrict__ Cout, int mode)
{
    const int tid = threadIdx.x;
    const int w = tid >> 6, lane = tid & 63;
    const int ln = lane & 15, quad = lane >> 4;
    const int bm = blockIdx.x * 128 + w * 32;
    const int bn = blockIdx.y * 64;
    f32x4 acc[2][4];
    #pragma unroll
    for (int mt = 0; mt < 2; ++mt)
        #pragma unroll
        for (int nt = 0; nt < 4; ++nt) acc[mt][nt] = (f32x4){0.f, 0.f, 0.f, 0.f};
    const us* pA[2][2];
    const us* pB[4][2];
    #pragma unroll
    for (int mt = 0; mt < 2; ++mt) {
        size_t r = (size_t)(bm + mt * 16 + ln) * 512 + quad * 8;
        pA[mt][0] = Ah + r; pA[mt][1] = Al + r;
    }
    #pragma unroll
    for (int nt = 0; nt < 4; ++nt) {
        size_t r = (size_t)(bn + nt * 16 + ln) * 512 + quad * 8;
        pB[nt][0] = BTh + r; pB[nt][1] = BTl + r;
    }
    #pragma unroll
    for (int ks = 0; ks < 16; ++ks) {
        const int ko = ks * 32;
        short8 Af[2][2], Bf[4][2];
        #pragma unroll
        for (int mt = 0; mt < 2; ++mt) {
            Af[mt][0] = *(const short8*)(pA[mt][0] + ko);
            Af[mt][1] = *(const short8*)(pA[mt][1] + ko);
        }
        #pragma unroll
        for (int nt = 0; nt < 4; ++nt) {
            Bf[nt][0] = *(const short8*)(pB[nt][0] + ko);
            Bf[nt][1] = *(const short8*)(pB[nt][1] + ko);
        }
        #pragma unroll
        for (int mt = 0; mt < 2; ++mt)
            #pragma unroll
            for (int nt = 0; nt < 4; ++nt) {
                acc[mt][nt] = mfma16(Af[mt][0], Bf[nt][0], acc[mt][nt]);
                acc[mt][nt] = mfma16(Af[mt][0], Bf[nt][1], acc[mt][nt]);
                acc[mt][nt] = mfma16(Af[mt][1], Bf[nt][0], acc[mt][nt]);
            }
    }
    #pragma unroll
    for (int mt = 0; mt < 2; ++mt)
        #pragma unroll
        for (int nt = 0; nt < 4; ++nt)
            #pragma unroll
            for (int r = 0; r < 4; ++r) {
                int m = bm + mt * 16 + quad * 4 + r;
                int n = bn + nt * 16 + ln;
                float v = acc[mt][nt][r];
                if (mode == 0) {
                    Cout[(size_t)m * 512 + n] = v;
                } else if (mode == 1) {
                    if (m < 4096) Cout[2 * ((size_t)m * 512 + n)] = v;
                    else          Cout[2 * ((size_t)(m - 4096) * 512 + n) + 1] = v;
                } else {
                    if (m < 4096) Cout[(size_t)m * 512 + n] = v;
                }
            }
}

// ---------------- complex gate: oh' = oh*g / (1 + exp(-2g)) ----------------
__global__ __launch_bounds__(256) void gate_kernel(
    const us* __restrict__ A1h, const us* __restrict__ A1l,
    const float* __restrict__ G,
    us* __restrict__ A2h, us* __restrict__ A2l, int n)
{
    int idx = (blockIdx.x * 256 + threadIdx.x) * 4;
    if (idx >= n) return;
    float4 grv = *(const float4*)&G[idx];
    float4 giv = *(const float4*)&G[idx + n];
    short4v hrh = *(const short4v*)&A1h[idx];
    short4v hrl = *(const short4v*)&A1l[idx];
    short4v hih = *(const short4v*)&A1h[n + idx];
    short4v hil = *(const short4v*)&A1l[n + idx];
    float grs[4] = {grv.x, grv.y, grv.z, grv.w};
    float gis[4] = {giv.x, giv.y, giv.z, giv.w};
    us rh[4], rl[4], ih_[4], il_[4];
    #pragma unroll
    for (int k = 0; k < 4; ++k) {
        float gr = grs[k], gi = gis[k];
        float hr = bf2f((us)hrh[k]) + bf2f((us)hrl[k]);
        float hi = bf2f((us)hih[k]) + bf2f((us)hil[k]);
        float e = expf(-2.0f * gr);
        float sn, cs;
        sincosf(2.0f * gi, &sn, &cs);
        float dr = 1.0f + e * cs;
        float di = -e * sn;
        float nr = hr * gr - hi * gi;
        float ni = hr * gi + hi * gr;
        float inv = 1.0f / (dr * dr + di * di);
        float o2r = (nr * dr + ni * di) * inv;
        float o2i = (ni * dr - nr * di) * inv;
        us t = f2bf(o2r); rh[k] = t; rl[k] = f2bf(o2r - bf2f(t));
        t = f2bf(o2i); ih_[k] = t; il_[k] = f2bf(o2i - bf2f(t));
    }
    *(short4v*)&A2h[idx]     = *(short4v*)&rh[0];
    *(short4v*)&A2l[idx]     = *(short4v*)&rl[0];
    *(short4v*)&A2h[n + idx] = *(short4v*)&ih_[0];
    *(short4v*)&A2l[n + idx] = *(short4v*)&il_[0];
}

extern "C" void kernel_launch(void* const* d_in, const int* in_sizes, int n_in,
                              void* d_out, int out_size, void* d_ws, size_t ws_size,
                              hipStream_t stream)
{
    const float* x     = (const float*)d_in[0];
    const float* WQ    = (const float*)d_in[1];
    const float* WK    = (const float*)d_in[2];
    const float* WV    = (const float*)d_in[3];
    const float* theta = (const float*)d_in[4];
    const float* gamma = (const float*)d_in[5];
    const float* qk    = (const float*)d_in[7];
    const float* WO    = (const float*)d_in[8];
    const float* WG    = (const float*)d_in[9];
    float* out = (float*)d_out;

    const size_t N1 = (size_t)B_ * H_ * C_ * HW_;       // 2,097,152
    const size_t SQ = (size_t)B_ * H_ * C_ * 128;       // 4,194,304 shorts
    const size_t SV = (size_t)B_ * H_ * HW_ * C_;       // 2,097,152 shorts
    us* usw = (us*)d_ws;
    us *Qch = usw,            *Qcl = usw + SQ,
       *K1h = usw + 2 * SQ,   *K1l = usw + 3 * SQ,
       *VTh = usw + 4 * SQ,   *VTl = usw + 4 * SQ + SV; // shorts end at 5*N1 floats
    float* fw = (float*)d_ws;
    us *A1h = (us*)(fw + 5 * N1), *A1l = (us*)(fw + 6 * N1);
    // WT overlays dead K1 (wcvt blocks run after retention):
    us *WTGh = K1h,            *WTGl = K1h + 262144,
       *WTOh = K1h + 524288,  *WTOl = K1h + 786432;
    float *G   = fw + 7 * N1;                           // 2*N1 fp32
    us *A2h = (us*)(fw + 9 * N1), *A2l = (us*)(fw + 10 * N1);
    // Pbuf = 3*N1 floats (768 x 8192) overlays G/A2h: dead before those write.
    float *Pbuf = fw + 7 * N1;

    proj_kernel<<<dim3(C_ / 32, B_ * H_), 256, 0, stream>>>(
        x, WQ, WK, WV, theta, Qch, Qcl, K1h, K1l, VTh, VTl);
    retention_kernel<<<dim3(768), 256, 0, stream>>>(
        Qch, Qcl, K1h, K1l, VTh, VTl, Pbuf, gamma, qk);
    reduce_wcvt_kernel<<<dim3(64, 16), 256, 0, stream>>>(
        Pbuf, A1h, A1l, WG, WO, WTGh, WTGl, WTOh, WTOl);

    gemm_mfma_kernel<<<dim3(64, 8), 256, 0, stream>>>(
        A1h, A1l, WTGh, WTGl, G, 0);

    int n1i = (int)N1;
    gate_kernel<<<dim3(n1i / 1024), 256, 0, stream>>>(
        A1h, A1l, G, A2h, A2l, n1i);

    int outmode = (out_size >= (int)(2 * N1)) ? 1 : 2;
    gemm_mfma_kernel<<<dim3(64, 8), 256, 0, stream>>>(
        A2h, A2l, WTOh, WTOl, out, outmode);
}

// Round 11
// 362.435 us; speedup vs baseline: 1.4410x; 1.4410x over previous
//
#include <hip/hip_runtime.h>
#include <cstdint>
#include <cstddef>

#define B_  2
#define H_  8
#define C_  2048
#define HW_ 64
#define HD_ 512   // H_*HW_

typedef __attribute__((ext_vector_type(8))) short short8;
typedef __attribute__((ext_vector_type(4))) short short4v;
typedef __attribute__((ext_vector_type(4))) float f32x4;
typedef __attribute__((ext_vector_type(4))) int   int4v;
typedef unsigned short us;

static __device__ inline us f2bf(float f) {           // RNE
    unsigned u = __builtin_bit_cast(unsigned, f);
    u = u + 0x7FFFu + ((u >> 16) & 1u);
    return (us)(u >> 16);
}
static __device__ inline us f2bf_t(float f) {         // truncate (hot path)
    return (us)(__builtin_bit_cast(unsigned, f) >> 16);
}
static __device__ inline float bf2f(us s) {
    unsigned u = ((unsigned)s) << 16;
    return __builtin_bit_cast(float, u);
}
static __device__ inline f32x4 mfma16(short8 a, short8 b, f32x4 c) {
    return __builtin_amdgcn_mfma_f32_16x16x32_bf16(a, b, c, 0, 0, 0);
}
static __device__ inline short8 negbf(short8 v) {
    int4v u = __builtin_bit_cast(int4v, v);
    u ^= (int)0x80008000;
    return __builtin_bit_cast(short8, u);
}
// b64-pair LDS fragment load (rows padded to 68 shorts -> only 8B-aligned)
static __device__ inline short8 lds_frag(const us* p) {
    short4v a = *(const short4v*)p;
    short4v b = *(const short4v*)(p + 4);
    return __builtin_shufflevector(a, b, 0, 1, 2, 3, 4, 5, 6, 7);
}

// ---------------- Projection + rotary phase ----------------
// W staged TRANSPOSED [j][i] (stride 68, 16B-aligned rows) -> float4 inner
// loop. CRITICAL (R10 lesson): inner loop unroll MUST be capped — full unroll
// of 16 iters x 11 float4 temps spilled to scratch (256 VGPR, 441 MB traffic).
__global__ __launch_bounds__(256) void proj_kernel(
    const float* __restrict__ x, const float* __restrict__ WQ,
    const float* __restrict__ WK, const float* __restrict__ WV,
    const float* __restrict__ theta,
    us* __restrict__ Qch, us* __restrict__ Qcl,
    us* __restrict__ K1h, us* __restrict__ K1l,
    us* __restrict__ VTh, us* __restrict__ VTl)
{
    __shared__ float smem[3 * 64 * 68 + 32 * 68];   // 60,928 B
    float* sWT = smem;               // [3][64 j][68 i]
    float* sx  = smem + 3 * 64 * 68; // [32 c][68 i]
    int tid = threadIdx.x;
    int bh = blockIdx.y; int h = bh & 7;
    int c0 = blockIdx.x * 32;
    for (int t = tid; t < 1024; t += 256) {
        int j4 = (t & 15) * 4, i = t >> 4;
        float4 wq = *(const float4*)&WQ[(h * 64 + i) * 64 + j4];
        float4 wk = *(const float4*)&WK[(h * 64 + i) * 64 + j4];
        float4 wv = *(const float4*)&WV[(h * 64 + i) * 64 + j4];
        sWT[(j4 + 0) * 68 + i] = wq.x; sWT[(j4 + 1) * 68 + i] = wq.y;
        sWT[(j4 + 2) * 68 + i] = wq.z; sWT[(j4 + 3) * 68 + i] = wq.w;
        sWT[64 * 68 + (j4 + 0) * 68 + i] = wk.x; sWT[64 * 68 + (j4 + 1) * 68 + i] = wk.y;
        sWT[64 * 68 + (j4 + 2) * 68 + i] = wk.z; sWT[64 * 68 + (j4 + 3) * 68 + i] = wk.w;
        sWT[2 * 64 * 68 + (j4 + 0) * 68 + i] = wv.x; sWT[2 * 64 * 68 + (j4 + 1) * 68 + i] = wv.y;
        sWT[2 * 64 * 68 + (j4 + 2) * 68 + i] = wv.z; sWT[2 * 64 * 68 + (j4 + 3) * 68 + i] = wv.w;
    }
    for (int t = tid; t < 512; t += 256) {
        int i4 = (t & 15) * 4, c = t >> 4;
        *(float4*)&sx[c * 68 + i4] =
            *(const float4*)&x[((size_t)((bh >> 3) * C_ + c0 + c)) * HD_ + h * 64 + i4];
    }
    __syncthreads();
    int j = tid & 63, cg = tid >> 6;     // cg uniform per wave
    float aq[8] = {}, ak[8] = {}, av[8] = {};
    const float* pw0 = &sWT[j * 68];
    const float* pw1 = &sWT[64 * 68 + j * 68];
    const float* pw2 = &sWT[2 * 64 * 68 + j * 68];
    const float* px  = &sx[cg * 8 * 68];
    #pragma unroll 2
    for (int i0 = 0; i0 < 64; i0 += 4) {
        float4 w0 = *(const float4*)(pw0 + i0);
        float4 w1 = *(const float4*)(pw1 + i0);
        float4 w2 = *(const float4*)(pw2 + i0);
        #pragma unroll
        for (int cc = 0; cc < 8; ++cc) {
            float4 xv = *(const float4*)(px + cc * 68 + i0);
            aq[cc] += xv.x * w0.x + xv.y * w0.y + xv.z * w0.z + xv.w * w0.w;
            ak[cc] += xv.x * w1.x + xv.y * w1.y + xv.z * w1.z + xv.w * w1.w;
            av[cc] += xv.x * w2.x + xv.y * w2.y + xv.z * w2.z + xv.w * w2.w;
        }
    }
    float th = theta[h * 64 + j];
    #pragma unroll
    for (int cc = 0; cc < 8; ++cc) {
        int c = c0 + cg * 8 + cc;
        float sn, cs;
        sincosf((float)c * th, &sn, &cs);
        float qr = aq[cc] * cs, qi = aq[cc] * sn;
        float kr = ak[cc] * cs, nki = ak[cc] * sn;   // nki = -Ki
        size_t rq = ((size_t)bh * C_ + c) * 128;
        us h0;
        h0 = f2bf(qr);  Qch[rq + j]      = h0; Qcl[rq + j]      = f2bf(qr  - bf2f(h0));
        h0 = f2bf(qi);  Qch[rq + 64 + j] = h0; Qcl[rq + 64 + j] = f2bf(qi  - bf2f(h0));
        h0 = f2bf(kr);  K1h[rq + j]      = h0; K1l[rq + j]      = f2bf(kr  - bf2f(h0));
        h0 = f2bf(nki); K1h[rq + 64 + j] = h0; K1l[rq + 64 + j] = f2bf(nki - bf2f(h0));
    }
    __syncthreads();
    float* T0 = smem;                   // [64][33]
    #pragma unroll
    for (int cc = 0; cc < 8; ++cc)
        T0[j * 33 + cg * 8 + cc] = av[cc];
    __syncthreads();
    int cc2 = tid & 31, jg = tid >> 5;
    #pragma unroll
    for (int jj = 0; jj < 8; ++jj) {
        int jr = jg * 8 + jj;
        float v = T0[jr * 33 + cc2];
        us hh = f2bf(v);
        size_t o = ((size_t)bh * 64 + jr) * C_ + c0 + cc2;
        VTh[o] = hh;
        VTl[o] = f2bf(v - bf2f(hh));
    }
}

// ---------------- MFMA Retention (split-K partials) ----------------
// EXACT R7 structure + schedule (measured 161 us best). R9/R10 lessons:
// V must be staged in LDS (global V = 4x duplicated VMEM, L1 thrash);
// do NOT schedule for a specific block->CU mapping (undefined) — big-first
// dispatch order only.
__global__ __launch_bounds__(256) void retention_kernel(
    const us* __restrict__ Qch, const us* __restrict__ Qcl,
    const us* __restrict__ K1h, const us* __restrict__ K1l,
    const us* __restrict__ VTh, const us* __restrict__ VTl,
    float* __restrict__ Pbuf,
    const float* __restrict__ gamma, const float* __restrict__ qk_scale)
{
    constexpr int SP = 68;
    constexpr int PL = 64 * SP;
    __shared__ us smem[6 * PL];        // 52,224 B -> 3 blocks/CU
    us* sSrh = smem;
    us* sSrl = smem + PL;
    us* sSih = smem + 2 * PL;
    us* sSil = smem + 3 * PL;
    us* sVh  = smem + 4 * PL;
    us* sVl  = smem + 5 * PL;

    const int tid = threadIdx.x;
    const int w = tid >> 6, lane = tid & 63;
    const int ln = lane & 15, quad = lane >> 4;
    const int r = (int)blockIdx.x >> 4, bh = (int)blockIdx.x & 15;
    const int h = bh & 7;
    int qt, klo, slot;
    if (r == 0)       { qt = 15; klo = 0;  slot = 15; }
    else if (r == 1)  { qt = 31; klo = 16; slot = 47; }
    else if (r <= 17) { qt = 14 + r; klo = 0; slot = 16 + 2 * (qt - 16); }
    else {
        int u = r - 18, s = 15 - (u >> 1);
        if ((u & 1) == 0) { qt = s - 1;  klo = 0;  slot = qt; }
        else              { qt = 15 + s; klo = 16; slot = 17 + 2 * (qt - 16); }
    }
    const int khi = (qt >= 16 && klo == 0) ? 15 : qt;
    const int qc0 = qt * 64;
    const float lg = log2f(gamma[h]);
    const float inv_scale = 1.0f / qk_scale[0];
    float rowf[4], colf[4];
    #pragma unroll
    for (int rr2 = 0; rr2 < 4; ++rr2)
        rowf[rr2] = exp2f(lg * (float)(w * 16 + quad * 4 + rr2));
    #pragma unroll
    for (int nt = 0; nt < 4; ++nt)
        colf[nt] = exp2f(-lg * (float)(nt * 16 + ln));

    short8 Qh[4], Ql[4];
    {
        size_t qrow = ((size_t)bh * C_ + qc0 + w * 16 + ln) * 128;
        #pragma unroll
        for (int ck = 0; ck < 4; ++ck) {
            size_t off = qrow + ck * 32 + quad * 8;
            Qh[ck] = *(const short8*)(Qch + off);
            Ql[ck] = *(const short8*)(Qcl + off);
        }
    }
    f32x4 zz = {0.0f, 0.0f, 0.0f, 0.0f};
    f32x4 Or[4], Oi[4];
    #pragma unroll
    for (int it = 0; it < 4; ++it) { Or[it] = zz; Oi[it] = zz; }

    const size_t vtb = (size_t)bh * 64 * C_;
    for (int kt = klo; kt <= khi; ++kt) {
        const int kc0 = kt * 64;
        __syncthreads();
        {
            int i = tid >> 2, seg = (tid & 3) * 16;
            size_t g = vtb + (size_t)i * C_ + kc0 + seg;
            short8 a = *(const short8*)(VTh + g);
            short8 bq = *(const short8*)(VTh + g + 8);
            *(short4v*)&sVh[i * SP + seg]      = __builtin_shufflevector(a, a, 0, 1, 2, 3);
            *(short4v*)&sVh[i * SP + seg + 4]  = __builtin_shufflevector(a, a, 4, 5, 6, 7);
            *(short4v*)&sVh[i * SP + seg + 8]  = __builtin_shufflevector(bq, bq, 0, 1, 2, 3);
            *(short4v*)&sVh[i * SP + seg + 12] = __builtin_shufflevector(bq, bq, 4, 5, 6, 7);
            a  = *(const short8*)(VTl + g);
            bq = *(const short8*)(VTl + g + 8);
            *(short4v*)&sVl[i * SP + seg]      = __builtin_shufflevector(a, a, 0, 1, 2, 3);
            *(short4v*)&sVl[i * SP + seg + 4]  = __builtin_shufflevector(a, a, 4, 5, 6, 7);
            *(short4v*)&sVl[i * SP + seg + 8]  = __builtin_shufflevector(bq, bq, 0, 1, 2, 3);
            *(short4v*)&sVl[i * SP + seg + 12] = __builtin_shufflevector(bq, bq, 4, 5, 6, 7);
        }
        const float tf = exp2f(lg * (float)(qc0 - kc0)) * inv_scale;
        float tr[4];
        #pragma unroll
        for (int rr2 = 0; rr2 < 4; ++rr2) tr[rr2] = tf * rowf[rr2];
        const bool diag = (kt == qt);
        #pragma unroll
        for (int nt = 0; nt < 4; ++nt) {
            short8 Kh[4], Kl[4];
            size_t krow = ((size_t)bh * C_ + kc0 + nt * 16 + ln) * 128;
            #pragma unroll
            for (int ck = 0; ck < 4; ++ck) {
                size_t off = krow + ck * 32 + quad * 8;
                Kh[ck] = *(const short8*)(K1h + off);
                Kl[ck] = *(const short8*)(K1l + off);
            }
            f32x4 sr = zz, si = zz;
            #pragma unroll
            for (int ck = 0; ck < 4; ++ck) {
                sr = mfma16(Qh[ck], Kh[ck], sr);
                sr = mfma16(Qh[ck], Kl[ck], sr);
                sr = mfma16(Ql[ck], Kh[ck], sr);
            }
            short8 nKh2 = negbf(Kh[2]), nKh3 = negbf(Kh[3]);
            short8 nKl2 = negbf(Kl[2]), nKl3 = negbf(Kl[3]);
            si = mfma16(Qh[0], nKh2, si); si = mfma16(Qh[0], nKl2, si); si = mfma16(Ql[0], nKh2, si);
            si = mfma16(Qh[1], nKh3, si); si = mfma16(Qh[1], nKl3, si); si = mfma16(Ql[1], nKh3, si);
            si = mfma16(Qh[2], Kh[0], si); si = mfma16(Qh[2], Kl[0], si); si = mfma16(Ql[2], Kh[0], si);
            si = mfma16(Qh[3], Kh[1], si); si = mfma16(Qh[3], Kl[1], si); si = mfma16(Ql[3], Kh[1], si);
            const int kL = nt * 16 + ln;
            #pragma unroll
            for (int rr2 = 0; rr2 < 4; ++rr2) {
                float wv = tr[rr2] * colf[nt];
                if (diag && (w * 16 + quad * 4 + rr2 < kL)) wv = 0.0f;
                float a = sr[rr2] * wv, c = si[rr2] * wv;
                int ad = (w * 16 + quad * 4 + rr2) * SP + nt * 16 + ln;
                us h0 = f2bf_t(a); sSrh[ad] = h0; sSrl[ad] = f2bf_t(a - bf2f(h0));
                us h1 = f2bf_t(c); sSih[ad] = h1; sSil[ad] = f2bf_t(c - bf2f(h1));
            }
        }
        __syncthreads();
        short8 SrH[2], SrL[2], SiH[2], SiL[2];
        int sb = (w * 16 + ln) * SP;
        #pragma unroll
        for (int ck2 = 0; ck2 < 2; ++ck2) {
            int off = sb + ck2 * 32 + quad * 8;
            SrH[ck2] = lds_frag(&sSrh[off]);
            SrL[ck2] = lds_frag(&sSrl[off]);
            SiH[ck2] = lds_frag(&sSih[off]);
            SiL[ck2] = lds_frag(&sSil[off]);
        }
        #pragma unroll
        for (int it = 0; it < 4; ++it) {
            int vb = (it * 16 + ln) * SP;
            #pragma unroll
            for (int ck2 = 0; ck2 < 2; ++ck2) {
                short8 Vh = lds_frag(&sVh[vb + ck2 * 32 + quad * 8]);
                short8 Vl = lds_frag(&sVl[vb + ck2 * 32 + quad * 8]);
                Or[it] = mfma16(SrH[ck2], Vh, Or[it]);
                Or[it] = mfma16(SrH[ck2], Vl, Or[it]);
                Or[it] = mfma16(SrL[ck2], Vh, Or[it]);
                Oi[it] = mfma16(SiH[ck2], Vh, Oi[it]);
                Oi[it] = mfma16(SiH[ck2], Vl, Oi[it]);
                Oi[it] = mfma16(SiL[ck2], Vh, Oi[it]);
            }
        }
    }
    float* Pr = Pbuf + ((size_t)(bh * 48 + slot)) * 8192;
    float* Pi = Pr + 4096;
    #pragma unroll
    for (int it = 0; it < 4; ++it) {
        #pragma unroll
        for (int rr2 = 0; rr2 < 4; ++rr2) {
            int qL = w * 16 + quad * 4 + rr2, iX = it * 16 + ln;
            Pr[qL * 64 + iX] = Or[it][rr2];
            Pi[qL * 64 + iX] = Oi[it][rr2];
        }
    }
}

// -------- Merged: partial reduce + L2 norm -> A1   AND   weight cvt --------
// grid (64, 16): bx<32 -> reduce (qt=bx, bh=by); bx>=32 -> wcvt tile.
__global__ __launch_bounds__(256) void reduce_wcvt_kernel(
    const float* __restrict__ Pbuf,
    us* __restrict__ A1h, us* __restrict__ A1l,
    const float* __restrict__ WG, const float* __restrict__ WO,
    us* __restrict__ Gh, us* __restrict__ Gl,
    us* __restrict__ Oh, us* __restrict__ Ol)
{
    __shared__ float T[32 * 33];
    if ((int)blockIdx.x < 32) {
        const int qt = blockIdx.x, bh = blockIdx.y;
        const int h = bh & 7, b = bh >> 3;
        const int t = threadIdx.x;
        const int q = t >> 2, i0 = (t & 3) * 16;
        const int slot0 = (qt < 16) ? qt : 16 + 2 * (qt - 16);
        const int nparts = (qt < 16) ? 1 : 2;
        const float* P0 = Pbuf + ((size_t)(bh * 48 + slot0)) * 8192 + q * 64 + i0;
        float orv[16], oiv[16];
        #pragma unroll
        for (int s4 = 0; s4 < 4; ++s4) {
            *(float4*)&orv[s4 * 4] = *(const float4*)(P0 + s4 * 4);
            *(float4*)&oiv[s4 * 4] = *(const float4*)(P0 + 4096 + s4 * 4);
        }
        if (nparts == 2) {
            const float* P1 = P0 + 8192;
            #pragma unroll
            for (int s4 = 0; s4 < 4; ++s4) {
                float4 a = *(const float4*)(P1 + s4 * 4);
                float4 c = *(const float4*)(P1 + 4096 + s4 * 4);
                orv[s4 * 4]     += a.x; orv[s4 * 4 + 1] += a.y;
                orv[s4 * 4 + 2] += a.z; orv[s4 * 4 + 3] += a.w;
                oiv[s4 * 4]     += c.x; oiv[s4 * 4 + 1] += c.y;
                oiv[s4 * 4 + 2] += c.z; oiv[s4 * 4 + 3] += c.w;
            }
        }
        float ss = 0.0f;
        #pragma unroll
        for (int k = 0; k < 16; ++k) ss += orv[k] * orv[k] + oiv[k] * oiv[k];
        ss += __shfl_xor(ss, 1);
        ss += __shfl_xor(ss, 2);
        float rn = rsqrtf(ss);
        const size_t N1 = (size_t)B_ * H_ * C_ * HW_;
        size_t o = (((size_t)(b * C_ + qt * 64 + q)) * H_ + h) * HW_ + i0;
        us th[16], tl[16];
        #pragma unroll
        for (int k = 0; k < 16; ++k) {
            float v = orv[k] * rn;
            us hh = f2bf(v); th[k] = hh; tl[k] = f2bf(v - bf2f(hh));
        }
        *(short8*)&A1h[o] = *(short8*)&th[0]; *(short8*)&A1h[o + 8] = *(short8*)&th[8];
        *(short8*)&A1l[o] = *(short8*)&tl[0]; *(short8*)&A1l[o + 8] = *(short8*)&tl[8];
        #pragma unroll
        for (int k = 0; k < 16; ++k) {
            float v = oiv[k] * rn;
            us hh = f2bf(v); th[k] = hh; tl[k] = f2bf(v - bf2f(hh));
        }
        *(short8*)&A1h[N1 + o] = *(short8*)&th[0]; *(short8*)&A1h[N1 + o + 8] = *(short8*)&th[8];
        *(short8*)&A1l[N1 + o] = *(short8*)&tl[0]; *(short8*)&A1l[N1 + o + 8] = *(short8*)&tl[8];
    } else {
        int widx = ((int)blockIdx.x - 32) * 16 + (int)blockIdx.y;  // 0..511
        int z = widx >> 8, w2 = widx & 255;
        const float* src = z ? WO : WG;
        us* dh = z ? Oh : Gh;
        us* dl = z ? Ol : Gl;
        int k0 = (w2 >> 4) * 32, n0 = (w2 & 15) * 32;
        int c = threadIdx.x & 31, r8 = threadIdx.x >> 5;
        #pragma unroll
        for (int rr = 0; rr < 4; ++rr) {
            int rw = r8 * 4 + rr;
            T[rw * 33 + c] = src[(size_t)(k0 + rw) * 512 + n0 + c];
        }
        __syncthreads();
        #pragma unroll
        for (int rr = 0; rr < 4; ++rr) {
            int rw = r8 * 4 + rr;           // n-local
            float v = T[c * 33 + rw];       // [k-local=c][n-local=rw]
            us hh = f2bf(v);
            size_t o = (size_t)(n0 + rw) * 512 + k0 + c;
            dh[o] = hh; dl[o] = f2bf(v - bf2f(hh));
        }
    }
}

// ---------------- split-bf16 MFMA GEMM: C[8192,512] = A * W (WT given) -----
__global__ __launch_bounds__(256) void gemm_mfma_kernel(
    const us* __restrict__ Ah, const us* __restrict__ Al,
    const us* __restrict__ BTh, const us* __restrict__ BTl,
    float* __restrict__ Cout, int mode)
{
    const int tid = threadIdx.x;
    const int w = tid >> 6, lane = tid & 63;
    const int ln = lane & 15, quad = lane >> 4;
    const int bm = blockIdx.x * 128 + w * 32;
    const int bn = blockIdx.y * 64;
    f32x4 acc[2][4];
    #pragma unroll
    for (int mt = 0; mt < 2; ++mt)
        #pragma unroll
        for (int nt = 0; nt < 4; ++nt) acc[mt][nt] = (f32x4){0.f, 0.f, 0.f, 0.f};
    const us* pA[2][2];
    const us* pB[4][2];
    #pragma unroll
    for (int mt = 0; mt < 2; ++mt) {
        size_t r = (size_t)(bm + mt * 16 + ln) * 512 + quad * 8;
        pA[mt][0] = Ah + r; pA[mt][1] = Al + r;
    }
    #pragma unroll
    for (int nt = 0; nt < 4; ++nt) {
        size_t r = (size_t)(bn + nt * 16 + ln) * 512 + quad * 8;
        pB[nt][0] = BTh + r; pB[nt][1] = BTl + r;
    }
    #pragma unroll
    for (int ks = 0; ks < 16; ++ks) {
        const int ko = ks * 32;
        short8 Af[2][2], Bf[4][2];
        #pragma unroll
        for (int mt = 0; mt < 2; ++mt) {
            Af[mt][0] = *(const short8*)(pA[mt][0] + ko);
            Af[mt][1] = *(const short8*)(pA[mt][1] + ko);
        }
        #pragma unroll
        for (int nt = 0; nt < 4; ++nt) {
            Bf[nt][0] = *(const short8*)(pB[nt][0] + ko);
            Bf[nt][1] = *(const short8*)(pB[nt][1] + ko);
        }
        #pragma unroll
        for (int mt = 0; mt < 2; ++mt)
            #pragma unroll
            for (int nt = 0; nt < 4; ++nt) {
                acc[mt][nt] = mfma16(Af[mt][0], Bf[nt][0], acc[mt][nt]);
                acc[mt][nt] = mfma16(Af[mt][0], Bf[nt][1], acc[mt][nt]);
                acc[mt][nt] = mfma16(Af[mt][1], Bf[nt][0], acc[mt][nt]);
            }
    }
    #pragma unroll
    for (int mt = 0; mt < 2; ++mt)
        #pragma unroll
        for (int nt = 0; nt < 4; ++nt)
            #pragma unroll
            for (int r = 0; r < 4; ++r) {
                int m = bm + mt * 16 + quad * 4 + r;
                int n = bn + nt * 16 + ln;
                float v = acc[mt][nt][r];
                if (mode == 0) {
                    Cout[(size_t)m * 512 + n] = v;
                } else if (mode == 1) {
                    if (m < 4096) Cout[2 * ((size_t)m * 512 + n)] = v;
                    else          Cout[2 * ((size_t)(m - 4096) * 512 + n) + 1] = v;
                } else {
                    if (m < 4096) Cout[(size_t)m * 512 + n] = v;
                }
            }
}

// ---------------- complex gate: oh' = oh*g / (1 + exp(-2g)) ----------------
__global__ __launch_bounds__(256) void gate_kernel(
    const us* __restrict__ A1h, const us* __restrict__ A1l,
    const float* __restrict__ G,
    us* __restrict__ A2h, us* __restrict__ A2l, int n)
{
    int idx = (blockIdx.x * 256 + threadIdx.x) * 4;
    if (idx >= n) return;
    float4 grv = *(const float4*)&G[idx];
    float4 giv = *(const float4*)&G[idx + n];
    short4v hrh = *(const short4v*)&A1h[idx];
    short4v hrl = *(const short4v*)&A1l[idx];
    short4v hih = *(const short4v*)&A1h[n + idx];
    short4v hil = *(const short4v*)&A1l[n + idx];
    float grs[4] = {grv.x, grv.y, grv.z, grv.w};
    float gis[4] = {giv.x, giv.y, giv.z, giv.w};
    us rh[4], rl[4], ih_[4], il_[4];
    #pragma unroll
    for (int k = 0; k < 4; ++k) {
        float gr = grs[k], gi = gis[k];
        float hr = bf2f((us)hrh[k]) + bf2f((us)hrl[k]);
        float hi = bf2f((us)hih[k]) + bf2f((us)hil[k]);
        float e = expf(-2.0f * gr);
        float sn, cs;
        sincosf(2.0f * gi, &sn, &cs);
        float dr = 1.0f + e * cs;
        float di = -e * sn;
        float nr = hr * gr - hi * gi;
        float ni = hr * gi + hi * gr;
        float inv = 1.0f / (dr * dr + di * di);
        float o2r = (nr * dr + ni * di) * inv;
        float o2i = (ni * dr - nr * di) * inv;
        us t = f2bf(o2r); rh[k] = t; rl[k] = f2bf(o2r - bf2f(t));
        t = f2bf(o2i); ih_[k] = t; il_[k] = f2bf(o2i - bf2f(t));
    }
    *(short4v*)&A2h[idx]     = *(short4v*)&rh[0];
    *(short4v*)&A2l[idx]     = *(short4v*)&rl[0];
    *(short4v*)&A2h[n + idx] = *(short4v*)&ih_[0];
    *(short4v*)&A2l[n + idx] = *(short4v*)&il_[0];
}

extern "C" void kernel_launch(void* const* d_in, const int* in_sizes, int n_in,
                              void* d_out, int out_size, void* d_ws, size_t ws_size,
                              hipStream_t stream)
{
    const float* x     = (const float*)d_in[0];
    const float* WQ    = (const float*)d_in[1];
    const float* WK    = (const float*)d_in[2];
    const float* WV    = (const float*)d_in[3];
    const float* theta = (const float*)d_in[4];
    const float* gamma = (const float*)d_in[5];
    const float* qk    = (const float*)d_in[7];
    const float* WO    = (const float*)d_in[8];
    const float* WG    = (const float*)d_in[9];
    float* out = (float*)d_out;

    const size_t N1 = (size_t)B_ * H_ * C_ * HW_;       // 2,097,152
    const size_t SQ = (size_t)B_ * H_ * C_ * 128;       // 4,194,304 shorts
    const size_t SV = (size_t)B_ * H_ * HW_ * C_;       // 2,097,152 shorts
    us* usw = (us*)d_ws;
    us *Qch = usw,            *Qcl = usw + SQ,
       *K1h = usw + 2 * SQ,   *K1l = usw + 3 * SQ,
       *VTh = usw + 4 * SQ,   *VTl = usw + 4 * SQ + SV; // shorts end at 5*N1 floats
    float* fw = (float*)d_ws;
    us *A1h = (us*)(fw + 5 * N1), *A1l = (us*)(fw + 6 * N1);
    // WT overlays dead K1 (wcvt blocks run after retention):
    us *WTGh = K1h,            *WTGl = K1h + 262144,
       *WTOh = K1h + 524288,  *WTOl = K1h + 786432;
    float *G   = fw + 7 * N1;                           // 2*N1 fp32
    us *A2h = (us*)(fw + 9 * N1), *A2l = (us*)(fw + 10 * N1);
    // Pbuf = 3*N1 floats (768 x 8192) overlays G/A2h: dead before those write.
    float *Pbuf = fw + 7 * N1;

    proj_kernel<<<dim3(C_ / 32, B_ * H_), 256, 0, stream>>>(
        x, WQ, WK, WV, theta, Qch, Qcl, K1h, K1l, VTh, VTl);
    retention_kernel<<<dim3(768), 256, 0, stream>>>(
        Qch, Qcl, K1h, K1l, VTh, VTl, Pbuf, gamma, qk);
    reduce_wcvt_kernel<<<dim3(64, 16), 256, 0, stream>>>(
        Pbuf, A1h, A1l, WG, WO, WTGh, WTGl, WTOh, WTOl);

    gemm_mfma_kernel<<<dim3(64, 8), 256, 0, stream>>>(
        A1h, A1l, WTGh, WTGl, G, 0);

    int n1i = (int)N1;
    gate_kernel<<<dim3(n1i / 1024), 256, 0, stream>>>(
        A1h, A1l, G, A2h, A2l, n1i);

    int outmode = (out_size >= (int)(2 * N1)) ? 1 : 2;
    gemm_mfma_kernel<<<dim3(64, 8), 256, 0, stream>>>(
        A2h, A2l, WTOh, WTOl, out, outmode);
}

// Round 12
// 361.862 us; speedup vs baseline: 1.4433x; 1.0016x over previous
//
#include <hip/hip_runtime.h>
#include <cstdint>
#include <cstddef>

#define B_  2
#define H_  8
#define C_  2048
#define HW_ 64
#define HD_ 512   // H_*HW_
#define N1_ 2097152  // B_*H_*C_*HW_

typedef __attribute__((ext_vector_type(8))) short short8;
typedef __attribute__((ext_vector_type(4))) short short4v;
typedef __attribute__((ext_vector_type(4))) float f32x4;
typedef __attribute__((ext_vector_type(4))) int   int4v;
typedef unsigned short us;

static __device__ inline us f2bf(float f) {           // RNE
    unsigned u = __builtin_bit_cast(unsigned, f);
    u = u + 0x7FFFu + ((u >> 16) & 1u);
    return (us)(u >> 16);
}
static __device__ inline us f2bf_t(float f) {         // truncate (hot path)
    return (us)(__builtin_bit_cast(unsigned, f) >> 16);
}
static __device__ inline float bf2f(us s) {
    unsigned u = ((unsigned)s) << 16;
    return __builtin_bit_cast(float, u);
}
static __device__ inline f32x4 mfma16(short8 a, short8 b, f32x4 c) {
    return __builtin_amdgcn_mfma_f32_16x16x32_bf16(a, b, c, 0, 0, 0);
}
static __device__ inline short8 negbf(short8 v) {
    int4v u = __builtin_bit_cast(int4v, v);
    u ^= (int)0x80008000;
    return __builtin_bit_cast(short8, u);
}
// b64-pair LDS fragment load (rows padded to 68 shorts -> only 8B-aligned)
static __device__ inline short8 lds_frag(const us* p) {
    short4v a = *(const short4v*)p;
    short4v b = *(const short4v*)(p + 4);
    return __builtin_shufflevector(a, b, 0, 1, 2, 3, 4, 5, 6, 7);
}

// ---------------- Projection + rotary phase ----------------
// W staged TRANSPOSED [j][i] (stride 68). R10 lesson: inner unroll capped at 2
// (full unroll spilled: 256 VGPR, 441 MB scratch traffic).
__global__ __launch_bounds__(256) void proj_kernel(
    const float* __restrict__ x, const float* __restrict__ WQ,
    const float* __restrict__ WK, const float* __restrict__ WV,
    const float* __restrict__ theta,
    us* __restrict__ Qch, us* __restrict__ Qcl,
    us* __restrict__ K1h, us* __restrict__ K1l,
    us* __restrict__ VTh, us* __restrict__ VTl)
{
    __shared__ float smem[3 * 64 * 68 + 32 * 68];   // 60,928 B
    float* sWT = smem;               // [3][64 j][68 i]
    float* sx  = smem + 3 * 64 * 68; // [32 c][68 i]
    int tid = threadIdx.x;
    int bh = blockIdx.y; int h = bh & 7;
    int c0 = blockIdx.x * 32;
    for (int t = tid; t < 1024; t += 256) {
        int j4 = (t & 15) * 4, i = t >> 4;
        float4 wq = *(const float4*)&WQ[(h * 64 + i) * 64 + j4];
        float4 wk = *(const float4*)&WK[(h * 64 + i) * 64 + j4];
        float4 wv = *(const float4*)&WV[(h * 64 + i) * 64 + j4];
        sWT[(j4 + 0) * 68 + i] = wq.x; sWT[(j4 + 1) * 68 + i] = wq.y;
        sWT[(j4 + 2) * 68 + i] = wq.z; sWT[(j4 + 3) * 68 + i] = wq.w;
        sWT[64 * 68 + (j4 + 0) * 68 + i] = wk.x; sWT[64 * 68 + (j4 + 1) * 68 + i] = wk.y;
        sWT[64 * 68 + (j4 + 2) * 68 + i] = wk.z; sWT[64 * 68 + (j4 + 3) * 68 + i] = wk.w;
        sWT[2 * 64 * 68 + (j4 + 0) * 68 + i] = wv.x; sWT[2 * 64 * 68 + (j4 + 1) * 68 + i] = wv.y;
        sWT[2 * 64 * 68 + (j4 + 2) * 68 + i] = wv.z; sWT[2 * 64 * 68 + (j4 + 3) * 68 + i] = wv.w;
    }
    for (int t = tid; t < 512; t += 256) {
        int i4 = (t & 15) * 4, c = t >> 4;
        *(float4*)&sx[c * 68 + i4] =
            *(const float4*)&x[((size_t)((bh >> 3) * C_ + c0 + c)) * HD_ + h * 64 + i4];
    }
    __syncthreads();
    int j = tid & 63, cg = tid >> 6;     // cg uniform per wave
    float aq[8] = {}, ak[8] = {}, av[8] = {};
    const float* pw0 = &sWT[j * 68];
    const float* pw1 = &sWT[64 * 68 + j * 68];
    const float* pw2 = &sWT[2 * 64 * 68 + j * 68];
    const float* px  = &sx[cg * 8 * 68];
    #pragma unroll 2
    for (int i0 = 0; i0 < 64; i0 += 4) {
        float4 w0 = *(const float4*)(pw0 + i0);
        float4 w1 = *(const float4*)(pw1 + i0);
        float4 w2 = *(const float4*)(pw2 + i0);
        #pragma unroll
        for (int cc = 0; cc < 8; ++cc) {
            float4 xv = *(const float4*)(px + cc * 68 + i0);
            aq[cc] += xv.x * w0.x + xv.y * w0.y + xv.z * w0.z + xv.w * w0.w;
            ak[cc] += xv.x * w1.x + xv.y * w1.y + xv.z * w1.z + xv.w * w1.w;
            av[cc] += xv.x * w2.x + xv.y * w2.y + xv.z * w2.z + xv.w * w2.w;
        }
    }
    float th = theta[h * 64 + j];
    #pragma unroll
    for (int cc = 0; cc < 8; ++cc) {
        int c = c0 + cg * 8 + cc;
        float sn, cs;
        sincosf((float)c * th, &sn, &cs);
        float qr = aq[cc] * cs, qi = aq[cc] * sn;
        float kr = ak[cc] * cs, nki = ak[cc] * sn;   // nki = -Ki
        size_t rq = ((size_t)bh * C_ + c) * 128;
        us h0;
        h0 = f2bf(qr);  Qch[rq + j]      = h0; Qcl[rq + j]      = f2bf(qr  - bf2f(h0));
        h0 = f2bf(qi);  Qch[rq + 64 + j] = h0; Qcl[rq + 64 + j] = f2bf(qi  - bf2f(h0));
        h0 = f2bf(kr);  K1h[rq + j]      = h0; K1l[rq + j]      = f2bf(kr  - bf2f(h0));
        h0 = f2bf(nki); K1h[rq + 64 + j] = h0; K1l[rq + 64 + j] = f2bf(nki - bf2f(h0));
    }
    __syncthreads();
    float* T0 = smem;                   // [64][33]
    #pragma unroll
    for (int cc = 0; cc < 8; ++cc)
        T0[j * 33 + cg * 8 + cc] = av[cc];
    __syncthreads();
    int cc2 = tid & 31, jg = tid >> 5;
    #pragma unroll
    for (int jj = 0; jj < 8; ++jj) {
        int jr = jg * 8 + jj;
        float v = T0[jr * 33 + cc2];
        us hh = f2bf(v);
        size_t o = ((size_t)bh * 64 + jr) * C_ + c0 + cc2;
        VTh[o] = hh;
        VTl[o] = f2bf(v - bf2f(hh));
    }
}

// ---------------- MFMA Retention (split-K partials) ----------------
// EXACT R7 structure + schedule (measured 158-161 us across 3 runs; four
// attempts to beat it all regressed — V in LDS, K from global, big-first).
__global__ __launch_bounds__(256) void retention_kernel(
    const us* __restrict__ Qch, const us* __restrict__ Qcl,
    const us* __restrict__ K1h, const us* __restrict__ K1l,
    const us* __restrict__ VTh, const us* __restrict__ VTl,
    float* __restrict__ Pbuf,
    const float* __restrict__ gamma, const float* __restrict__ qk_scale)
{
    constexpr int SP = 68;
    constexpr int PL = 64 * SP;
    __shared__ us smem[6 * PL];        // 52,224 B -> 3 blocks/CU
    us* sSrh = smem;
    us* sSrl = smem + PL;
    us* sSih = smem + 2 * PL;
    us* sSil = smem + 3 * PL;
    us* sVh  = smem + 4 * PL;
    us* sVl  = smem + 5 * PL;

    const int tid = threadIdx.x;
    const int w = tid >> 6, lane = tid & 63;
    const int ln = lane & 15, quad = lane >> 4;
    const int r = (int)blockIdx.x >> 4, bh = (int)blockIdx.x & 15;
    const int h = bh & 7;
    int qt, klo, slot;
    if (r == 0)       { qt = 15; klo = 0;  slot = 15; }
    else if (r == 1)  { qt = 31; klo = 16; slot = 47; }
    else if (r <= 17) { qt = 14 + r; klo = 0; slot = 16 + 2 * (qt - 16); }
    else {
        int u = r - 18, s = 15 - (u >> 1);
        if ((u & 1) == 0) { qt = s - 1;  klo = 0;  slot = qt; }
        else              { qt = 15 + s; klo = 16; slot = 17 + 2 * (qt - 16); }
    }
    const int khi = (qt >= 16 && klo == 0) ? 15 : qt;
    const int qc0 = qt * 64;
    const float lg = log2f(gamma[h]);
    const float inv_scale = 1.0f / qk_scale[0];
    float rowf[4], colf[4];
    #pragma unroll
    for (int rr2 = 0; rr2 < 4; ++rr2)
        rowf[rr2] = exp2f(lg * (float)(w * 16 + quad * 4 + rr2));
    #pragma unroll
    for (int nt = 0; nt < 4; ++nt)
        colf[nt] = exp2f(-lg * (float)(nt * 16 + ln));

    short8 Qh[4], Ql[4];
    {
        size_t qrow = ((size_t)bh * C_ + qc0 + w * 16 + ln) * 128;
        #pragma unroll
        for (int ck = 0; ck < 4; ++ck) {
            size_t off = qrow + ck * 32 + quad * 8;
            Qh[ck] = *(const short8*)(Qch + off);
            Ql[ck] = *(const short8*)(Qcl + off);
        }
    }
    f32x4 zz = {0.0f, 0.0f, 0.0f, 0.0f};
    f32x4 Or[4], Oi[4];
    #pragma unroll
    for (int it = 0; it < 4; ++it) { Or[it] = zz; Oi[it] = zz; }

    const size_t vtb = (size_t)bh * 64 * C_;
    for (int kt = klo; kt <= khi; ++kt) {
        const int kc0 = kt * 64;
        __syncthreads();
        {
            int i = tid >> 2, seg = (tid & 3) * 16;
            size_t g = vtb + (size_t)i * C_ + kc0 + seg;
            short8 a = *(const short8*)(VTh + g);
            short8 bq = *(const short8*)(VTh + g + 8);
            *(short4v*)&sVh[i * SP + seg]      = __builtin_shufflevector(a, a, 0, 1, 2, 3);
            *(short4v*)&sVh[i * SP + seg + 4]  = __builtin_shufflevector(a, a, 4, 5, 6, 7);
            *(short4v*)&sVh[i * SP + seg + 8]  = __builtin_shufflevector(bq, bq, 0, 1, 2, 3);
            *(short4v*)&sVh[i * SP + seg + 12] = __builtin_shufflevector(bq, bq, 4, 5, 6, 7);
            a  = *(const short8*)(VTl + g);
            bq = *(const short8*)(VTl + g + 8);
            *(short4v*)&sVl[i * SP + seg]      = __builtin_shufflevector(a, a, 0, 1, 2, 3);
            *(short4v*)&sVl[i * SP + seg + 4]  = __builtin_shufflevector(a, a, 4, 5, 6, 7);
            *(short4v*)&sVl[i * SP + seg + 8]  = __builtin_shufflevector(bq, bq, 0, 1, 2, 3);
            *(short4v*)&sVl[i * SP + seg + 12] = __builtin_shufflevector(bq, bq, 4, 5, 6, 7);
        }
        const float tf = exp2f(lg * (float)(qc0 - kc0)) * inv_scale;
        float tr[4];
        #pragma unroll
        for (int rr2 = 0; rr2 < 4; ++rr2) tr[rr2] = tf * rowf[rr2];
        const bool diag = (kt == qt);
        #pragma unroll
        for (int nt = 0; nt < 4; ++nt) {
            short8 Kh[4], Kl[4];
            size_t krow = ((size_t)bh * C_ + kc0 + nt * 16 + ln) * 128;
            #pragma unroll
            for (int ck = 0; ck < 4; ++ck) {
                size_t off = krow + ck * 32 + quad * 8;
                Kh[ck] = *(const short8*)(K1h + off);
                Kl[ck] = *(const short8*)(K1l + off);
            }
            f32x4 sr = zz, si = zz;
            #pragma unroll
            for (int ck = 0; ck < 4; ++ck) {
                sr = mfma16(Qh[ck], Kh[ck], sr);
                sr = mfma16(Qh[ck], Kl[ck], sr);
                sr = mfma16(Ql[ck], Kh[ck], sr);
            }
            short8 nKh2 = negbf(Kh[2]), nKh3 = negbf(Kh[3]);
            short8 nKl2 = negbf(Kl[2]), nKl3 = negbf(Kl[3]);
            si = mfma16(Qh[0], nKh2, si); si = mfma16(Qh[0], nKl2, si); si = mfma16(Ql[0], nKh2, si);
            si = mfma16(Qh[1], nKh3, si); si = mfma16(Qh[1], nKl3, si); si = mfma16(Ql[1], nKh3, si);
            si = mfma16(Qh[2], Kh[0], si); si = mfma16(Qh[2], Kl[0], si); si = mfma16(Ql[2], Kh[0], si);
            si = mfma16(Qh[3], Kh[1], si); si = mfma16(Qh[3], Kl[1], si); si = mfma16(Ql[3], Kh[1], si);
            const int kL = nt * 16 + ln;
            #pragma unroll
            for (int rr2 = 0; rr2 < 4; ++rr2) {
                float wv = tr[rr2] * colf[nt];
                if (diag && (w * 16 + quad * 4 + rr2 < kL)) wv = 0.0f;
                float a = sr[rr2] * wv, c = si[rr2] * wv;
                int ad = (w * 16 + quad * 4 + rr2) * SP + nt * 16 + ln;
                us h0 = f2bf_t(a); sSrh[ad] = h0; sSrl[ad] = f2bf_t(a - bf2f(h0));
                us h1 = f2bf_t(c); sSih[ad] = h1; sSil[ad] = f2bf_t(c - bf2f(h1));
            }
        }
        __syncthreads();
        short8 SrH[2], SrL[2], SiH[2], SiL[2];
        int sb = (w * 16 + ln) * SP;
        #pragma unroll
        for (int ck2 = 0; ck2 < 2; ++ck2) {
            int off = sb + ck2 * 32 + quad * 8;
            SrH[ck2] = lds_frag(&sSrh[off]);
            SrL[ck2] = lds_frag(&sSrl[off]);
            SiH[ck2] = lds_frag(&sSih[off]);
            SiL[ck2] = lds_frag(&sSil[off]);
        }
        #pragma unroll
        for (int it = 0; it < 4; ++it) {
            int vb = (it * 16 + ln) * SP;
            #pragma unroll
            for (int ck2 = 0; ck2 < 2; ++ck2) {
                short8 Vh = lds_frag(&sVh[vb + ck2 * 32 + quad * 8]);
                short8 Vl = lds_frag(&sVl[vb + ck2 * 32 + quad * 8]);
                Or[it] = mfma16(SrH[ck2], Vh, Or[it]);
                Or[it] = mfma16(SrH[ck2], Vl, Or[it]);
                Or[it] = mfma16(SrL[ck2], Vh, Or[it]);
                Oi[it] = mfma16(SiH[ck2], Vh, Oi[it]);
                Oi[it] = mfma16(SiH[ck2], Vl, Oi[it]);
                Oi[it] = mfma16(SiL[ck2], Vh, Oi[it]);
            }
        }
    }
    float* Pr = Pbuf + ((size_t)(bh * 48 + slot)) * 8192;
    float* Pi = Pr + 4096;
    #pragma unroll
    for (int it = 0; it < 4; ++it) {
        #pragma unroll
        for (int rr2 = 0; rr2 < 4; ++rr2) {
            int qL = w * 16 + quad * 4 + rr2, iX = it * 16 + ln;
            Pr[qL * 64 + iX] = Or[it][rr2];
            Pi[qL * 64 + iX] = Oi[it][rr2];
        }
    }
}

// -------- Merged: partial reduce + L2 norm -> A1   AND   weight cvt --------
// grid (64, 16): bx<32 -> reduce (qt=bx, bh=by); bx>=32 -> wcvt tile.
__global__ __launch_bounds__(256) void reduce_wcvt_kernel(
    const float* __restrict__ Pbuf,
    us* __restrict__ A1h, us* __restrict__ A1l,
    const float* __restrict__ WG, const float* __restrict__ WO,
    us* __restrict__ Gh, us* __restrict__ Gl,
    us* __restrict__ Oh, us* __restrict__ Ol)
{
    __shared__ float T[32 * 33];
    if ((int)blockIdx.x < 32) {
        const int qt = blockIdx.x, bh = blockIdx.y;
        const int h = bh & 7, b = bh >> 3;
        const int t = threadIdx.x;
        const int q = t >> 2, i0 = (t & 3) * 16;
        const int slot0 = (qt < 16) ? qt : 16 + 2 * (qt - 16);
        const int nparts = (qt < 16) ? 1 : 2;
        const float* P0 = Pbuf + ((size_t)(bh * 48 + slot0)) * 8192 + q * 64 + i0;
        float orv[16], oiv[16];
        #pragma unroll
        for (int s4 = 0; s4 < 4; ++s4) {
            *(float4*)&orv[s4 * 4] = *(const float4*)(P0 + s4 * 4);
            *(float4*)&oiv[s4 * 4] = *(const float4*)(P0 + 4096 + s4 * 4);
        }
        if (nparts == 2) {
            const float* P1 = P0 + 8192;
            #pragma unroll
            for (int s4 = 0; s4 < 4; ++s4) {
                float4 a = *(const float4*)(P1 + s4 * 4);
                float4 c = *(const float4*)(P1 + 4096 + s4 * 4);
                orv[s4 * 4]     += a.x; orv[s4 * 4 + 1] += a.y;
                orv[s4 * 4 + 2] += a.z; orv[s4 * 4 + 3] += a.w;
                oiv[s4 * 4]     += c.x; oiv[s4 * 4 + 1] += c.y;
                oiv[s4 * 4 + 2] += c.z; oiv[s4 * 4 + 3] += c.w;
            }
        }
        float ss = 0.0f;
        #pragma unroll
        for (int k = 0; k < 16; ++k) ss += orv[k] * orv[k] + oiv[k] * oiv[k];
        ss += __shfl_xor(ss, 1);
        ss += __shfl_xor(ss, 2);
        float rn = rsqrtf(ss);
        size_t o = (((size_t)(b * C_ + qt * 64 + q)) * H_ + h) * HW_ + i0;
        us th[16], tl[16];
        #pragma unroll
        for (int k = 0; k < 16; ++k) {
            float v = orv[k] * rn;
            us hh = f2bf(v); th[k] = hh; tl[k] = f2bf(v - bf2f(hh));
        }
        *(short8*)&A1h[o] = *(short8*)&th[0]; *(short8*)&A1h[o + 8] = *(short8*)&th[8];
        *(short8*)&A1l[o] = *(short8*)&tl[0]; *(short8*)&A1l[o + 8] = *(short8*)&tl[8];
        #pragma unroll
        for (int k = 0; k < 16; ++k) {
            float v = oiv[k] * rn;
            us hh = f2bf(v); th[k] = hh; tl[k] = f2bf(v - bf2f(hh));
        }
        *(short8*)&A1h[N1_ + o] = *(short8*)&th[0]; *(short8*)&A1h[N1_ + o + 8] = *(short8*)&th[8];
        *(short8*)&A1l[N1_ + o] = *(short8*)&tl[0]; *(short8*)&A1l[N1_ + o + 8] = *(short8*)&tl[8];
    } else {
        int widx = ((int)blockIdx.x - 32) * 16 + (int)blockIdx.y;  // 0..511
        int z = widx >> 8, w2 = widx & 255;
        const float* src = z ? WO : WG;
        us* dh = z ? Oh : Gh;
        us* dl = z ? Ol : Gl;
        int k0 = (w2 >> 4) * 32, n0 = (w2 & 15) * 32;
        int c = threadIdx.x & 31, r8 = threadIdx.x >> 5;
        #pragma unroll
        for (int rr = 0; rr < 4; ++rr) {
            int rw = r8 * 4 + rr;
            T[rw * 33 + c] = src[(size_t)(k0 + rw) * 512 + n0 + c];
        }
        __syncthreads();
        #pragma unroll
        for (int rr = 0; rr < 4; ++rr) {
            int rw = r8 * 4 + rr;           // n-local
            float v = T[c * 33 + rw];       // [k-local=c][n-local=rw]
            us hh = f2bf(v);
            size_t o = (size_t)(n0 + rw) * 512 + k0 + c;
            dh[o] = hh; dl[o] = f2bf(v - bf2f(hh));
        }
    }
}

// ------- Fused G-GEMM + complex gate: A2 = gate(A1, A1*WG) -----------------
// grid (32, 8): each block computes the re-plane tile (rows bm..bm+127) AND
// the matching im-plane tile (rows +4096) so every thread holds (G_re, G_im)
// at the same (m,n) in its accumulators — gate applied in-register, G never
// written to memory. A1/A2 row layout: rows 0..4095 = re, 4096..8191 = im.
__global__ __launch_bounds__(256) void gemm_gate_kernel(
    const us* __restrict__ Ah, const us* __restrict__ Al,
    const us* __restrict__ BTh, const us* __restrict__ BTl,
    us* __restrict__ A2h, us* __restrict__ A2l)
{
    const int tid = threadIdx.x;
    const int w = tid >> 6, lane = tid & 63;
    const int ln = lane & 15, quad = lane >> 4;
    const int bm = blockIdx.x * 128 + w * 32;   // re-plane rows [0,4096)
    const int bn = blockIdx.y * 64;
    f32x4 accR[2][4], accI[2][4];
    #pragma unroll
    for (int mt = 0; mt < 2; ++mt)
        #pragma unroll
        for (int nt = 0; nt < 4; ++nt) {
            accR[mt][nt] = (f32x4){0.f, 0.f, 0.f, 0.f};
            accI[mt][nt] = (f32x4){0.f, 0.f, 0.f, 0.f};
        }
    const us* pAr[2][2];
    const us* pAi[2][2];
    const us* pB[4][2];
    #pragma unroll
    for (int mt = 0; mt < 2; ++mt) {
        size_t rr = (size_t)(bm + mt * 16 + ln) * 512 + quad * 8;
        pAr[mt][0] = Ah + rr;        pAr[mt][1] = Al + rr;
        pAi[mt][0] = Ah + N1_ + rr;  pAi[mt][1] = Al + N1_ + rr;
    }
    #pragma unroll
    for (int nt = 0; nt < 4; ++nt) {
        size_t rr = (size_t)(bn + nt * 16 + ln) * 512 + quad * 8;
        pB[nt][0] = BTh + rr; pB[nt][1] = BTl + rr;
    }
    #pragma unroll 4
    for (int ks = 0; ks < 16; ++ks) {
        const int ko = ks * 32;
        short8 Ar[2][2], Ai[2][2], Bf[4][2];
        #pragma unroll
        for (int mt = 0; mt < 2; ++mt) {
            Ar[mt][0] = *(const short8*)(pAr[mt][0] + ko);
            Ar[mt][1] = *(const short8*)(pAr[mt][1] + ko);
            Ai[mt][0] = *(const short8*)(pAi[mt][0] + ko);
            Ai[mt][1] = *(const short8*)(pAi[mt][1] + ko);
        }
        #pragma unroll
        for (int nt = 0; nt < 4; ++nt) {
            Bf[nt][0] = *(const short8*)(pB[nt][0] + ko);
            Bf[nt][1] = *(const short8*)(pB[nt][1] + ko);
        }
        #pragma unroll
        for (int mt = 0; mt < 2; ++mt)
            #pragma unroll
            for (int nt = 0; nt < 4; ++nt) {
                accR[mt][nt] = mfma16(Ar[mt][0], Bf[nt][0], accR[mt][nt]);
                accR[mt][nt] = mfma16(Ar[mt][0], Bf[nt][1], accR[mt][nt]);
                accR[mt][nt] = mfma16(Ar[mt][1], Bf[nt][0], accR[mt][nt]);
                accI[mt][nt] = mfma16(Ai[mt][0], Bf[nt][0], accI[mt][nt]);
                accI[mt][nt] = mfma16(Ai[mt][0], Bf[nt][1], accI[mt][nt]);
                accI[mt][nt] = mfma16(Ai[mt][1], Bf[nt][0], accI[mt][nt]);
            }
    }
    // epilogue: gate in-register, write A2 bf16 h/l (fully unrolled — R1/R10)
    #pragma unroll
    for (int mt = 0; mt < 2; ++mt)
        #pragma unroll
        for (int nt = 0; nt < 4; ++nt)
            #pragma unroll
            for (int r = 0; r < 4; ++r) {
                int m = bm + mt * 16 + quad * 4 + r;
                int n = bn + nt * 16 + ln;
                size_t idx = (size_t)m * 512 + n;
                float gr = accR[mt][nt][r], gi = accI[mt][nt][r];
                float hr = bf2f(Ah[idx]) + bf2f(Al[idx]);
                float hi = bf2f(Ah[N1_ + idx]) + bf2f(Al[N1_ + idx]);
                float e = expf(-2.0f * gr);
                float sn, cs;
                sincosf(2.0f * gi, &sn, &cs);
                float dr = 1.0f + e * cs;
                float di = -e * sn;
                float nr = hr * gr - hi * gi;
                float ni = hr * gi + hi * gr;
                float inv = 1.0f / (dr * dr + di * di);
                float o2r = (nr * dr + ni * di) * inv;
                float o2i = (ni * dr - nr * di) * inv;
                us t = f2bf(o2r);
                A2h[idx] = t; A2l[idx] = f2bf(o2r - bf2f(t));
                t = f2bf(o2i);
                A2h[N1_ + idx] = t; A2l[N1_ + idx] = f2bf(o2i - bf2f(t));
            }
}

// ---------------- split-bf16 MFMA GEMM: C[8192,512] = A * W (WT given) -----
__global__ __launch_bounds__(256) void gemm_mfma_kernel(
    const us* __restrict__ Ah, const us* __restrict__ Al,
    const us* __restrict__ BTh, const us* __restrict__ BTl,
    float* __restrict__ Cout, int mode)
{
    const int tid = threadIdx.x;
    const int w = tid >> 6, lane = tid & 63;
    const int ln = lane & 15, quad = lane >> 4;
    const int bm = blockIdx.x * 128 + w * 32;
    const int bn = blockIdx.y * 64;
    f32x4 acc[2][4];
    #pragma unroll
    for (int mt = 0; mt < 2; ++mt)
        #pragma unroll
        for (int nt = 0; nt < 4; ++nt) acc[mt][nt] = (f32x4){0.f, 0.f, 0.f, 0.f};
    const us* pA[2][2];
    const us* pB[4][2];
    #pragma unroll
    for (int mt = 0; mt < 2; ++mt) {
        size_t r = (size_t)(bm + mt * 16 + ln) * 512 + quad * 8;
        pA[mt][0] = Ah + r; pA[mt][1] = Al + r;
    }
    #pragma unroll
    for (int nt = 0; nt < 4; ++nt) {
        size_t r = (size_t)(bn + nt * 16 + ln) * 512 + quad * 8;
        pB[nt][0] = BTh + r; pB[nt][1] = BTl + r;
    }
    #pragma unroll
    for (int ks = 0; ks < 16; ++ks) {
        const int ko = ks * 32;
        short8 Af[2][2], Bf[4][2];
        #pragma unroll
        for (int mt = 0; mt < 2; ++mt) {
            Af[mt][0] = *(const short8*)(pA[mt][0] + ko);
            Af[mt][1] = *(const short8*)(pA[mt][1] + ko);
        }
        #pragma unroll
        for (int nt = 0; nt < 4; ++nt) {
            Bf[nt][0] = *(const short8*)(pB[nt][0] + ko);
            Bf[nt][1] = *(const short8*)(pB[nt][1] + ko);
        }
        #pragma unroll
        for (int mt = 0; mt < 2; ++mt)
            #pragma unroll
            for (int nt = 0; nt < 4; ++nt) {
                acc[mt][nt] = mfma16(Af[mt][0], Bf[nt][0], acc[mt][nt]);
                acc[mt][nt] = mfma16(Af[mt][0], Bf[nt][1], acc[mt][nt]);
                acc[mt][nt] = mfma16(Af[mt][1], Bf[nt][0], acc[mt][nt]);
            }
    }
    #pragma unroll
    for (int mt = 0; mt < 2; ++mt)
        #pragma unroll
        for (int nt = 0; nt < 4; ++nt)
            #pragma unroll
            for (int r = 0; r < 4; ++r) {
                int m = bm + mt * 16 + quad * 4 + r;
                int n = bn + nt * 16 + ln;
                float v = acc[mt][nt][r];
                if (mode == 0) {
                    Cout[(size_t)m * 512 + n] = v;
                } else if (mode == 1) {
                    if (m < 4096) Cout[2 * ((size_t)m * 512 + n)] = v;
                    else          Cout[2 * ((size_t)(m - 4096) * 512 + n) + 1] = v;
                } else {
                    if (m < 4096) Cout[(size_t)m * 512 + n] = v;
                }
            }
}

extern "C" void kernel_launch(void* const* d_in, const int* in_sizes, int n_in,
                              void* d_out, int out_size, void* d_ws, size_t ws_size,
                              hipStream_t stream)
{
    const float* x     = (const float*)d_in[0];
    const float* WQ    = (const float*)d_in[1];
    const float* WK    = (const float*)d_in[2];
    const float* WV    = (const float*)d_in[3];
    const float* theta = (const float*)d_in[4];
    const float* gamma = (const float*)d_in[5];
    const float* qk    = (const float*)d_in[7];
    const float* WO    = (const float*)d_in[8];
    const float* WG    = (const float*)d_in[9];
    float* out = (float*)d_out;

    const size_t N1 = (size_t)B_ * H_ * C_ * HW_;       // 2,097,152
    const size_t SQ = (size_t)B_ * H_ * C_ * 128;       // 4,194,304 shorts
    const size_t SV = (size_t)B_ * H_ * HW_ * C_;       // 2,097,152 shorts
    us* usw = (us*)d_ws;
    us *Qch = usw,            *Qcl = usw + SQ,
       *K1h = usw + 2 * SQ,   *K1l = usw + 3 * SQ,
       *VTh = usw + 4 * SQ,   *VTl = usw + 4 * SQ + SV; // shorts end at 5*N1 floats
    float* fw = (float*)d_ws;
    us *A1h = (us*)(fw + 5 * N1), *A1l = (us*)(fw + 6 * N1);
    // WT overlays dead K1 (wcvt blocks run after retention):
    us *WTGh = K1h,            *WTGl = K1h + 262144,
       *WTOh = K1h + 524288,  *WTOl = K1h + 786432;
    us *A2h = (us*)(fw + 9 * N1), *A2l = (us*)(fw + 10 * N1);
    // Pbuf = 3*N1 floats (768 x 8192) spans [7N1,10N1): dead before
    // gemm_gate writes A2 (9N1..11N1) — reduce consumed it already.
    float *Pbuf = fw + 7 * N1;

    proj_kernel<<<dim3(C_ / 32, B_ * H_), 256, 0, stream>>>(
        x, WQ, WK, WV, theta, Qch, Qcl, K1h, K1l, VTh, VTl);
    retention_kernel<<<dim3(768), 256, 0, stream>>>(
        Qch, Qcl, K1h, K1l, VTh, VTl, Pbuf, gamma, qk);
    reduce_wcvt_kernel<<<dim3(64, 16), 256, 0, stream>>>(
        Pbuf, A1h, A1l, WG, WO, WTGh, WTGl, WTOh, WTOl);

    gemm_gate_kernel<<<dim3(32, 8), 256, 0, stream>>>(
        A1h, A1l, WTGh, WTGl, A2h, A2l);

    int outmode = (out_size >= (int)(2 * N1)) ? 1 : 2;
    gemm_mfma_kernel<<<dim3(64, 8), 256, 0, stream>>>(
        A2h, A2l, WTOh, WTOl, out, outmode);
}